// Round 15
// baseline (203.528 us; speedup 1.0000x reference)
//
#include <hip/hip_runtime.h>

#define N_NODES 20000
#define N_EDGES 320000
#define IN_F    168
#define HID     256
#define K1P     192   // GEMM-1 K (IN_F zero-padded to multiple of 64)
#define XS      192   // xb row stride in shorts (384B, 128B-aligned)
#define NF4     42    // IN_F / 4
#define NSCAN   20    // scan blocks (1024 nodes each)

typedef __attribute__((ext_vector_type(8))) short bf16x8;
typedef __attribute__((ext_vector_type(4))) float f32x4;

__device__ __forceinline__ short f2bf(float f) {
    union { float f; unsigned u; } v; v.f = f;
    unsigned r = v.u + 0x7FFFu + ((v.u >> 16) & 1u);
    return (short)(r >> 16);
}
__device__ __forceinline__ float bf2f(short s) {
    union { unsigned u; float f; } v; v.u = ((unsigned)(unsigned short)s) << 16;
    return v.f;
}

// build 20-entry exclusive prefix of bsum in LDS (call from wave 0, then sync)
__device__ __forceinline__ void build_pfx(const int* __restrict__ bsum, int* pfx,
                                          int tid) {
    if (tid < 64) {
        int v = (tid < NSCAN) ? bsum[tid] : 0;
        int incl = v;
        #pragma unroll
        for (int d = 1; d < 32; d <<= 1) {
            int t = __shfl_up(incl, d);
            if ((tid & 63) >= d) incl += t;
        }
        if (tid < NSCAN) pfx[tid] = incl - v;
    }
}

// ---------------- fused prep: x->bf16 (192-padded), W->bf16, edge deg/count ----

__global__ void prep_all(const float* __restrict__ x, short* __restrict__ xb,
                         const float* __restrict__ W1, const float* __restrict__ W2,
                         short* __restrict__ w1b, short* __restrict__ w2b,
                         const int* __restrict__ ei, const float* __restrict__ ew,
                         float* __restrict__ deg, int* __restrict__ counts) {
    int b = blockIdx.x;
    int k = threadIdx.x;
    if (b < N_NODES) {
        if (k >= XS) return;
        float v = (k < IN_F) ? x[(size_t)b * IN_F + k] : 0.f;
        xb[(size_t)b * XS + k] = f2bf(v);
        return;
    }
    b -= N_NODES;
    if (b < 256) {
        if (k >= K1P) return;
        float v = (k < IN_F) ? W1[(size_t)b * IN_F + k] : 0.f;
        w1b[(size_t)b * K1P + k] = f2bf(v);
        return;
    }
    if (b < 512) {
        int r = b - 256;
        w2b[(size_t)r * HID + k] = f2bf(W2[(size_t)r * HID + k]);
        return;
    }
    int e = (b - 512) * 256 + k;
    if (e < N_EDGES) {
        int d = ei[N_EDGES + e];
        atomicAdd(&deg[d], ew[e]);
        atomicAdd(&counts[d], 1);
    }
}

// ---------------- scan (block-local) ----------------
// offs[i] = block-local exclusive prefix; bsum[b] = block total; deg -> dinv.
// Consumers add pfx[i>>10] (exclusive prefix of bsum) on the fly.

__global__ __launch_bounds__(1024) void scan_part(const int* __restrict__ counts,
                                                  int* __restrict__ offs,
                                                  int* __restrict__ bsum,
                                                  float* __restrict__ deg, int n) {
    int tid  = threadIdx.x;
    int lane = tid & 63;
    int wv   = tid >> 6;
    int i = blockIdx.x * 1024 + tid;
    if (i < n) deg[i] = rsqrtf(deg[i] + 1.0f);     // self-loop weight 1.0
    __shared__ int wsum[16];
    int v = (i < n) ? counts[i] : 0;
    int incl = v;
    #pragma unroll
    for (int d = 1; d < 64; d <<= 1) {
        int t = __shfl_up(incl, d);
        if (lane >= d) incl += t;
    }
    if (lane == 63) wsum[wv] = incl;
    __syncthreads();
    if (wv == 0) {
        int w = (lane < 16) ? wsum[lane] : 0;
        int winc = w;
        #pragma unroll
        for (int d = 1; d < 16; d <<= 1) {
            int t = __shfl_up(winc, d);
            if (lane >= d) winc += t;
        }
        if (lane < 16) wsum[lane] = winc - w;
    }
    __syncthreads();
    if (i <= n) offs[i] = wsum[wv] + incl - v;     // includes offs[n] (v=0 there)
    if (tid == 1023) bsum[blockIdx.x] = wsum[15] + incl;
}

// packed edge record: .x = src node, .y = norm as float bits
__global__ void scatter_edges(const int* __restrict__ ei, const float* __restrict__ ew,
                              const float* __restrict__ dinv, const int* __restrict__ offs,
                              const int* __restrict__ bsum,
                              int* __restrict__ cursor, int2* __restrict__ er) {
    __shared__ int pfx[NSCAN];
    build_pfx(bsum, pfx, threadIdx.x);
    __syncthreads();
    int e = blockIdx.x * blockDim.x + threadIdx.x;
    if (e >= N_EDGES) return;
    int s = ei[e];
    int d = ei[N_EDGES + e];
    int pos = offs[d] + pfx[d >> 10] + atomicAdd(&cursor[d], 1);
    float nm = dinv[s] * ew[e] * dinv[d];
    er[pos] = make_int2(s, __float_as_int(nm));
}

// ---------------- gathers (Agg BEFORE GEMM; emit bf16 A operand) ----------------
// 16-deep ILP primary tier (avg degree 16): ~64 cache-line requests in flight/wave.

#define AGG_PFX()                                                       \
    __shared__ int pfx[NSCAN];                                          \
    build_pfx(bsum, pfx, threadIdx.x);                                  \
    __syncthreads();

#define AGG_TIER(D, SRC, STRIDE, LO)                                    \
    for (; p + D <= p1; p += D) {                                       \
        int2 e[D]; short4 r[D];                                         \
        _Pragma("unroll")                                               \
        for (int j = 0; j < D; ++j) e[j] = er[p + j];                   \
        _Pragma("unroll")                                               \
        for (int j = 0; j < D; ++j)                                     \
            r[j] = *(const short4*)(SRC + (size_t)e[j].x * STRIDE + LO);\
        _Pragma("unroll")                                               \
        for (int j = 0; j < D; ++j) {                                   \
            float w = __int_as_float(e[j].y);                           \
            a0 += w * bf2f(r[j].x); a1 += w * bf2f(r[j].y);             \
            a2 += w * bf2f(r[j].z); a3 += w * bf2f(r[j].w);             \
        }                                                               \
    }

// layer 1: agg from bf16 xb rows (384B stride); lanes 0..41 own short4.
__global__ __launch_bounds__(256) void agg_x(const short* __restrict__ xb,
                                             const float* __restrict__ dinv,
                                             const int* __restrict__ offs,
                                             const int* __restrict__ bsum,
                                             const int2* __restrict__ er,
                                             short* __restrict__ ax) {
    AGG_PFX();
    int wave = threadIdx.x >> 6;
    int lane = threadIdx.x & 63;
    int n = blockIdx.x * 4 + wave;
    bool act = lane < NF4;
    int lo4 = act ? lane * 4 : 0;                  // inactive lanes read row start (safe)
    float di = dinv[n];
    float sw = di * di;
    short4 sv = *(const short4*)(xb + (size_t)n * XS + lo4);
    float a0 = sw * bf2f(sv.x), a1 = sw * bf2f(sv.y);
    float a2 = sw * bf2f(sv.z), a3 = sw * bf2f(sv.w);

    int p0 = offs[n] + pfx[n >> 10];
    int p1 = offs[n + 1] + pfx[(n + 1) >> 10];
    int p = p0;
    AGG_TIER(16, xb, XS, lo4)
    AGG_TIER(8,  xb, XS, lo4)
    AGG_TIER(4,  xb, XS, lo4)
    for (; p < p1; ++p) {
        int2 e0 = er[p];
        float w0 = __int_as_float(e0.y);
        short4 r0 = *(const short4*)(xb + (size_t)e0.x * XS + lo4);
        a0 += w0 * bf2f(r0.x); a1 += w0 * bf2f(r0.y);
        a2 += w0 * bf2f(r0.z); a3 += w0 * bf2f(r0.w);
    }

    size_t base = (size_t)n * K1P + lane * 4;
    if (act) {
        *(short4*)&ax[base] = make_short4(f2bf(a0), f2bf(a1), f2bf(a2), f2bf(a3));
    } else if (lane < 48) {                        // zero pad cols 168..191
        *(short4*)&ax[base] = make_short4(0, 0, 0, 0);
    }
}

// layer 2: agg from bf16 h1 rows (512B); one short4 per lane.
__global__ __launch_bounds__(256) void agg_h(const short* __restrict__ h1h,
                                             const float* __restrict__ dinv,
                                             const int* __restrict__ offs,
                                             const int* __restrict__ bsum,
                                             const int2* __restrict__ er,
                                             short* __restrict__ ah) {
    AGG_PFX();
    int wave = threadIdx.x >> 6;
    int lane = threadIdx.x & 63;
    int n = blockIdx.x * 4 + wave;
    int lo4 = lane * 4;
    float di = dinv[n];
    float sw = di * di;
    short4 sv = *(const short4*)(h1h + (size_t)n * HID + lo4);
    float a0 = sw * bf2f(sv.x), a1 = sw * bf2f(sv.y);
    float a2 = sw * bf2f(sv.z), a3 = sw * bf2f(sv.w);

    int p0 = offs[n] + pfx[n >> 10];
    int p1 = offs[n + 1] + pfx[(n + 1) >> 10];
    int p = p0;
    AGG_TIER(16, h1h, HID, lo4)
    AGG_TIER(8,  h1h, HID, lo4)
    AGG_TIER(4,  h1h, HID, lo4)
    for (; p < p1; ++p) {
        int2 e0 = er[p];
        float w0 = __int_as_float(e0.y);
        short4 r0 = *(const short4*)(h1h + (size_t)e0.x * HID + lo4);
        a0 += w0 * bf2f(r0.x); a1 += w0 * bf2f(r0.y);
        a2 += w0 * bf2f(r0.z); a3 += w0 * bf2f(r0.w);
    }

    size_t base = (size_t)n * HID + lo4;
    *(short4*)&ah[base] = make_short4(f2bf(a0), f2bf(a1), f2bf(a2), f2bf(a3));
}

// ---------------- MFMA GEMM (pure bf16) with fused bias+ReLU epilogue ----------
// C[M,256] = relu(A[M,K] * W[256,K]^T + bias), A and W bf16 (RNE), fp32 MFMA acc.
// 64x64 tile, 4 waves each 32x32 (2x2 MFMA 16x16x32), BK=64, LDS-staged,
// register prefetch, XCD-affinity swizzle. mode 0: bf16 out; mode 1: fp32 out.

#define LDS_STRIDE 72

__global__ __launch_bounds__(256) void gemm_bf(const short* __restrict__ Ah,
                                               const short* __restrict__ Wh,
                                               const float* __restrict__ bias,
                                               float* __restrict__ Cf,
                                               short* __restrict__ Cbf,
                                               int M, int Ks, int nsteps, int mode) {
    __shared__ short sAh[64 * LDS_STRIDE];
    __shared__ short sWh[64 * LDS_STRIDE];

    // swizzle: idx = group*32 + slot*8 + xcd  ->  mt = group*8 + xcd, nt = slot
    const int idx   = blockIdx.x;
    const int group = idx >> 5;
    const int xcd   = idx & 7;
    const int slot  = (idx >> 3) & 3;
    const int mt    = group * 8 + xcd;
    const int mtiles = (M + 63) >> 6;
    if (mt >= mtiles) return;
    const int bm = mt * 64;
    const int bn = slot * 64;

    const int tid  = threadIdx.x;
    const int lane = tid & 63;
    const int wv   = tid >> 6;
    const int l16  = lane & 15;
    const int quad = lane >> 4;
    const int wm   = (wv & 1) * 32;
    const int wn   = (wv >> 1) * 32;

    const int srow = tid >> 2;
    const int sseg = (tid & 3) * 16;
    int arow = bm + srow; if (arow >= M) arow = M - 1;
    const short* gAh = Ah + (size_t)arow * Ks;
    const short* gWh = Wh + (size_t)(bn + srow) * Ks;
    const int lds_off = srow * LDS_STRIDE + sseg;

    f32x4 acc00 = {0,0,0,0}, acc01 = {0,0,0,0}, acc10 = {0,0,0,0}, acc11 = {0,0,0,0};

    int4 pah0 = *(const int4*)(gAh + sseg), pah1 = *(const int4*)(gAh + sseg + 8);
    int4 pwh0 = *(const int4*)(gWh + sseg), pwh1 = *(const int4*)(gWh + sseg + 8);

    for (int ks = 0; ks < nsteps; ++ks) {
        *(int4*)&sAh[lds_off] = pah0; *(int4*)&sAh[lds_off + 8] = pah1;
        *(int4*)&sWh[lds_off] = pwh0; *(int4*)&sWh[lds_off + 8] = pwh1;
        __syncthreads();
        if (ks + 1 < nsteps) {
            int o = (ks + 1) * 64 + sseg;
            pah0 = *(const int4*)(gAh + o); pah1 = *(const int4*)(gAh + o + 8);
            pwh0 = *(const int4*)(gWh + o); pwh1 = *(const int4*)(gWh + o + 8);
        }
        #pragma unroll
        for (int o = 0; o < 2; ++o) {
            const int a0 = (wm + l16) * LDS_STRIDE + o * 32 + quad * 8;
            const int a1 = a0 + 16 * LDS_STRIDE;
            const int w0 = (wn + l16) * LDS_STRIDE + o * 32 + quad * 8;
            const int w1 = w0 + 16 * LDS_STRIDE;
            bf16x8 ah0 = *(const bf16x8*)&sAh[a0];
            bf16x8 ah1 = *(const bf16x8*)&sAh[a1];
            bf16x8 wh0 = *(const bf16x8*)&sWh[w0];
            bf16x8 wh1 = *(const bf16x8*)&sWh[w1];
            acc00 = __builtin_amdgcn_mfma_f32_16x16x32_bf16(ah0, wh0, acc00, 0, 0, 0);
            acc01 = __builtin_amdgcn_mfma_f32_16x16x32_bf16(ah0, wh1, acc01, 0, 0, 0);
            acc10 = __builtin_amdgcn_mfma_f32_16x16x32_bf16(ah1, wh0, acc10, 0, 0, 0);
            acc11 = __builtin_amdgcn_mfma_f32_16x16x32_bf16(ah1, wh1, acc11, 0, 0, 0);
        }
        __syncthreads();
    }

    const int colb = bn + wn + l16;
    const int rowb = bm + wm + quad * 4;
    const float b0 = bias[colb];
    const float b1 = bias[colb + 16];
    #pragma unroll
    for (int r = 0; r < 4; ++r) {
        int row = rowb + r;
        if (row < M) {
            float v0 = acc00[r] + b0; v0 = v0 > 0.f ? v0 : 0.f;
            float v1 = acc01[r] + b1; v1 = v1 > 0.f ? v1 : 0.f;
            if (mode == 0) {
                Cbf[(size_t)row * HID + colb]      = f2bf(v0);
                Cbf[(size_t)row * HID + colb + 16] = f2bf(v1);
            } else {
                Cf[(size_t)row * HID + colb]      = v0;
                Cf[(size_t)row * HID + colb + 16] = v1;
            }
        }
        int row2 = row + 16;
        if (row2 < M) {
            float v0 = acc10[r] + b0; v0 = v0 > 0.f ? v0 : 0.f;
            float v1 = acc11[r] + b1; v1 = v1 > 0.f ? v1 : 0.f;
            if (mode == 0) {
                Cbf[(size_t)row2 * HID + colb]      = f2bf(v0);
                Cbf[(size_t)row2 * HID + colb + 16] = f2bf(v1);
            } else {
                Cf[(size_t)row2 * HID + colb]      = v0;
                Cf[(size_t)row2 * HID + colb + 16] = v1;
            }
        }
    }
}

// ---------------- launch ----------------

extern "C" void kernel_launch(void* const* d_in, const int* in_sizes, int n_in,
                              void* d_out, int out_size, void* d_ws, size_t ws_size,
                              hipStream_t stream) {
    const float* x  = (const float*)d_in[0];
    const int*   ei = (const int*)d_in[1];
    const float* ew = (const float*)d_in[2];
    const float* W1 = (const float*)d_in[3];
    const float* b1 = (const float*)d_in[4];
    const float* W2 = (const float*)d_in[5];
    const float* b2 = (const float*)d_in[6];
    float* out = (float*)d_out;

    char* ws = (char*)d_ws;
    float* deg      = (float*)(ws);                 // 20000 f32 (becomes dinv)
    int*   counts   = (int*)(ws + 80000);           // 20000 i32
    int*   cursor   = (int*)(ws + 160000);          // 20000 i32
    int*   offs     = (int*)(ws + 240000);          // 20001 i32 (block-local)
    int*   bsum     = (int*)(ws + 320016);          // 20 i32 (pad to 320144)
    int2*  er       = (int2*)(ws + 320144);         // 320000 int2 -> 2880144
    // region A: ax (20000x192 bf16, 7.68MB) dead after gemm1; reused for ah
    short* ax       = (short*)(ws + 2880144);       // -> 10560144
    short* ah       = (short*)(ws + 2880144);       // 20000x256 -> 13120144
    short* h1h      = (short*)(ws + 23360144);      // 20000x256 bf16 -> 33600144
    short* w1b      = (short*)(ws + 33600144);      // 256x192 -> 33698448
    short* w2b      = (short*)(ws + 33698448);      // 256x256 -> 33829520
    short* xb       = (short*)(ws + 34058896);      // 20000x192 bf16 -> 41738896

    hipMemsetAsync(d_ws, 0, 240000, stream);        // deg, counts, cursor

    const int TB = 256;
    prep_all<<<N_NODES + 512 + (N_EDGES + 255) / 256, 256, 0, stream>>>(
        x, xb, W1, W2, w1b, w2b, ei, ew, deg, counts);
    scan_part<<<NSCAN, 1024, 0, stream>>>(counts, offs, bsum, deg, N_NODES);
    scatter_edges<<<(N_EDGES + TB - 1) / TB, TB, 0, stream>>>(ei, ew, deg, offs, bsum,
                                                              cursor, er);

    const int mtiles = (N_NODES + 63) / 64;          // 313
    const int gemm_grid = ((mtiles + 7) / 8) * 32;   // 1280
    // layer 1: Agg(bf16 xb) -> bf16; GEMM(+b1, ReLU) -> h1 bf16
    agg_x<<<N_NODES / 4, 256, 0, stream>>>(xb, deg, offs, bsum, er, ax);
    gemm_bf<<<gemm_grid, 256, 0, stream>>>(ax, w1b, b1, nullptr, h1h,
                                           N_NODES, K1P, 3, 0);
    // layer 2: Agg(bf16 h1) -> bf16; GEMM(+b2, ReLU) -> out fp32
    agg_h<<<N_NODES / 4, 256, 0, stream>>>(h1h, deg, offs, bsum, er, ah);
    gemm_bf<<<gemm_grid, 256, 0, stream>>>(ah, w2b, b2, out, nullptr,
                                           N_NODES, HID, 4, 1);
}

// Round 16
// 201.158 us; speedup vs baseline: 1.0118x; 1.0118x over previous
//
#include <hip/hip_runtime.h>

#define N_NODES 20000
#define N_EDGES 320000
#define IN_F    168
#define HID     256
#define K1P     192   // GEMM-1 K (IN_F zero-padded to multiple of 64)
#define XS      192   // xb row stride in shorts (384B, 128B-aligned)
#define NF4     42    // IN_F / 4

typedef __attribute__((ext_vector_type(8))) short bf16x8;
typedef __attribute__((ext_vector_type(4))) float f32x4;

__device__ __forceinline__ short f2bf(float f) {
    union { float f; unsigned u; } v; v.f = f;
    unsigned r = v.u + 0x7FFFu + ((v.u >> 16) & 1u);
    return (short)(r >> 16);
}
__device__ __forceinline__ float bf2f(short s) {
    union { unsigned u; float f; } v; v.u = ((unsigned)(unsigned short)s) << 16;
    return v.f;
}

// ---------------- fused prep: x->bf16 (192-padded), W->bf16, edge deg/count ----

__global__ void prep_all(const float* __restrict__ x, short* __restrict__ xb,
                         const float* __restrict__ W1, const float* __restrict__ W2,
                         short* __restrict__ w1b, short* __restrict__ w2b,
                         const int* __restrict__ ei, const float* __restrict__ ew,
                         float* __restrict__ deg, int* __restrict__ counts) {
    int b = blockIdx.x;
    int k = threadIdx.x;
    if (b < N_NODES) {
        if (k >= XS) return;
        float v = (k < IN_F) ? x[(size_t)b * IN_F + k] : 0.f;
        xb[(size_t)b * XS + k] = f2bf(v);
        return;
    }
    b -= N_NODES;
    if (b < 256) {
        if (k >= K1P) return;
        float v = (k < IN_F) ? W1[(size_t)b * IN_F + k] : 0.f;
        w1b[(size_t)b * K1P + k] = f2bf(v);
        return;
    }
    if (b < 512) {
        int r = b - 256;
        w2b[(size_t)r * HID + k] = f2bf(W2[(size_t)r * HID + k]);
        return;
    }
    int e = (b - 512) * 256 + k;
    if (e < N_EDGES) {
        int d = ei[N_EDGES + e];
        atomicAdd(&deg[d], ew[e]);
        atomicAdd(&counts[d], 1);
    }
}

// ---------------- scan (2-kernel) + scatter ----------------

__global__ __launch_bounds__(1024) void scan_part(const int* __restrict__ counts,
                                                  int* __restrict__ offs,
                                                  int* __restrict__ bsum,
                                                  float* __restrict__ deg, int n) {
    int tid  = threadIdx.x;
    int lane = tid & 63;
    int wv   = tid >> 6;
    int i = blockIdx.x * 1024 + tid;
    if (i < n) deg[i] = rsqrtf(deg[i] + 1.0f);     // self-loop weight 1.0
    __shared__ int wsum[16];
    int v = (i < n) ? counts[i] : 0;
    int incl = v;
    #pragma unroll
    for (int d = 1; d < 64; d <<= 1) {
        int t = __shfl_up(incl, d);
        if (lane >= d) incl += t;
    }
    if (lane == 63) wsum[wv] = incl;
    __syncthreads();
    if (wv == 0) {
        int w = (lane < 16) ? wsum[lane] : 0;
        int winc = w;
        #pragma unroll
        for (int d = 1; d < 16; d <<= 1) {
            int t = __shfl_up(winc, d);
            if (lane >= d) winc += t;
        }
        if (lane < 16) wsum[lane] = winc - w;
    }
    __syncthreads();
    if (i < n) offs[i] = wsum[wv] + incl - v;
    if (tid == 1023) bsum[blockIdx.x] = wsum[15] + incl;
}

__global__ __launch_bounds__(1024) void scan_add(const int* __restrict__ bsum,
                                                 int* __restrict__ offs, int n) {
    int i = blockIdx.x * 1024 + threadIdx.x;
    int add = 0;
    for (int b = 0; b < (int)blockIdx.x; ++b) add += bsum[b];
    if (i < n) offs[i] += add;
    if (i == n) offs[n] = add + bsum[blockIdx.x];
}

// packed edge record: .x = src node, .y = norm as float bits
__global__ void scatter_edges(const int* __restrict__ ei, const float* __restrict__ ew,
                              const float* __restrict__ dinv, const int* __restrict__ offs,
                              int* __restrict__ cursor, int2* __restrict__ er) {
    int e = blockIdx.x * blockDim.x + threadIdx.x;
    if (e >= N_EDGES) return;
    int s = ei[e];
    int d = ei[N_EDGES + e];
    int pos = offs[d] + atomicAdd(&cursor[d], 1);
    float nm = dinv[s] * ew[e] * dinv[d];
    er[pos] = make_int2(s, __float_as_int(nm));
}

// ---------------- gathers (Agg BEFORE GEMM; emit bf16 A operand) ----------------

// layer 1: agg from bf16 xb rows (384B stride); lanes 0..41 own short4.
__global__ __launch_bounds__(256) void agg_x(const short* __restrict__ xb,
                                             const float* __restrict__ dinv,
                                             const int* __restrict__ offs,
                                             const int2* __restrict__ er,
                                             short* __restrict__ ax) {
    int wave = threadIdx.x >> 6;
    int lane = threadIdx.x & 63;
    int n = blockIdx.x * 4 + wave;
    bool act = lane < NF4;
    int lo4 = act ? lane * 4 : 0;                  // inactive lanes read row start (safe)
    float di = dinv[n];
    float sw = di * di;
    short4 sv = *(const short4*)(xb + (size_t)n * XS + lo4);
    float a0 = sw * bf2f(sv.x), a1 = sw * bf2f(sv.y);
    float a2 = sw * bf2f(sv.z), a3 = sw * bf2f(sv.w);

    int p0 = offs[n], p1 = offs[n + 1];
    int p = p0;
    for (; p + 8 <= p1; p += 8) {
        int2 e[8]; short4 r[8];
        #pragma unroll
        for (int j = 0; j < 8; ++j) e[j] = er[p + j];
        #pragma unroll
        for (int j = 0; j < 8; ++j) r[j] = *(const short4*)(xb + (size_t)e[j].x * XS + lo4);
        #pragma unroll
        for (int j = 0; j < 8; ++j) {
            float w = __int_as_float(e[j].y);
            a0 += w * bf2f(r[j].x); a1 += w * bf2f(r[j].y);
            a2 += w * bf2f(r[j].z); a3 += w * bf2f(r[j].w);
        }
    }
    for (; p + 4 <= p1; p += 4) {
        int2 e[4]; short4 r[4];
        #pragma unroll
        for (int j = 0; j < 4; ++j) e[j] = er[p + j];
        #pragma unroll
        for (int j = 0; j < 4; ++j) r[j] = *(const short4*)(xb + (size_t)e[j].x * XS + lo4);
        #pragma unroll
        for (int j = 0; j < 4; ++j) {
            float w = __int_as_float(e[j].y);
            a0 += w * bf2f(r[j].x); a1 += w * bf2f(r[j].y);
            a2 += w * bf2f(r[j].z); a3 += w * bf2f(r[j].w);
        }
    }
    for (; p < p1; ++p) {
        int2 e0 = er[p];
        float w0 = __int_as_float(e0.y);
        short4 r0 = *(const short4*)(xb + (size_t)e0.x * XS + lo4);
        a0 += w0 * bf2f(r0.x); a1 += w0 * bf2f(r0.y);
        a2 += w0 * bf2f(r0.z); a3 += w0 * bf2f(r0.w);
    }

    size_t base = (size_t)n * K1P + lane * 4;
    if (act) {
        *(short4*)&ax[base] = make_short4(f2bf(a0), f2bf(a1), f2bf(a2), f2bf(a3));
    } else if (lane < 48) {                        // zero pad cols 168..191
        *(short4*)&ax[base] = make_short4(0, 0, 0, 0);
    }
}

// layer 2: agg from bf16 h1 rows (512B); one short4 per lane; 8-deep ILP.
__global__ __launch_bounds__(256) void agg_h(const short* __restrict__ h1h,
                                             const float* __restrict__ dinv,
                                             const int* __restrict__ offs,
                                             const int2* __restrict__ er,
                                             short* __restrict__ ah) {
    int wave = threadIdx.x >> 6;
    int lane = threadIdx.x & 63;
    int n = blockIdx.x * 4 + wave;
    int lo4 = lane * 4;
    float di = dinv[n];
    float sw = di * di;
    short4 sv = *(const short4*)(h1h + (size_t)n * HID + lo4);
    float a0 = sw * bf2f(sv.x), a1 = sw * bf2f(sv.y);
    float a2 = sw * bf2f(sv.z), a3 = sw * bf2f(sv.w);

    int p0 = offs[n], p1 = offs[n + 1];
    int p = p0;
    for (; p + 8 <= p1; p += 8) {
        int2 e[8]; short4 r[8];
        #pragma unroll
        for (int j = 0; j < 8; ++j) e[j] = er[p + j];
        #pragma unroll
        for (int j = 0; j < 8; ++j) r[j] = *(const short4*)(h1h + (size_t)e[j].x * HID + lo4);
        #pragma unroll
        for (int j = 0; j < 8; ++j) {
            float w = __int_as_float(e[j].y);
            a0 += w * bf2f(r[j].x); a1 += w * bf2f(r[j].y);
            a2 += w * bf2f(r[j].z); a3 += w * bf2f(r[j].w);
        }
    }
    for (; p + 4 <= p1; p += 4) {
        int2 e[4]; short4 r[4];
        #pragma unroll
        for (int j = 0; j < 4; ++j) e[j] = er[p + j];
        #pragma unroll
        for (int j = 0; j < 4; ++j) r[j] = *(const short4*)(h1h + (size_t)e[j].x * HID + lo4);
        #pragma unroll
        for (int j = 0; j < 4; ++j) {
            float w = __int_as_float(e[j].y);
            a0 += w * bf2f(r[j].x); a1 += w * bf2f(r[j].y);
            a2 += w * bf2f(r[j].z); a3 += w * bf2f(r[j].w);
        }
    }
    for (; p < p1; ++p) {
        int2 e0 = er[p];
        float w0 = __int_as_float(e0.y);
        short4 r0 = *(const short4*)(h1h + (size_t)e0.x * HID + lo4);
        a0 += w0 * bf2f(r0.x); a1 += w0 * bf2f(r0.y);
        a2 += w0 * bf2f(r0.z); a3 += w0 * bf2f(r0.w);
    }

    size_t base = (size_t)n * HID + lo4;
    *(short4*)&ah[base] = make_short4(f2bf(a0), f2bf(a1), f2bf(a2), f2bf(a3));
}

// ---------------- MFMA GEMM (pure bf16) with fused bias+ReLU epilogue ----------
// C[M,256] = relu(A[M,K] * W[256,K]^T + bias), A and W bf16 (RNE), fp32 MFMA acc.
// 64x64 tile, 4 waves each 32x32 (2x2 MFMA 16x16x32), BK=64, LDS-staged,
// register prefetch, XCD-affinity swizzle. mode 0: bf16 out; mode 1: fp32 out.

#define LDS_STRIDE 72

__global__ __launch_bounds__(256) void gemm_bf(const short* __restrict__ Ah,
                                               const short* __restrict__ Wh,
                                               const float* __restrict__ bias,
                                               float* __restrict__ Cf,
                                               short* __restrict__ Cbf,
                                               int M, int Ks, int nsteps, int mode) {
    __shared__ short sAh[64 * LDS_STRIDE];
    __shared__ short sWh[64 * LDS_STRIDE];

    // swizzle: idx = group*32 + slot*8 + xcd  ->  mt = group*8 + xcd, nt = slot
    const int idx   = blockIdx.x;
    const int group = idx >> 5;
    const int xcd   = idx & 7;
    const int slot  = (idx >> 3) & 3;
    const int mt    = group * 8 + xcd;
    const int mtiles = (M + 63) >> 6;
    if (mt >= mtiles) return;
    const int bm = mt * 64;
    const int bn = slot * 64;

    const int tid  = threadIdx.x;
    const int lane = tid & 63;
    const int wv   = tid >> 6;
    const int l16  = lane & 15;
    const int quad = lane >> 4;
    const int wm   = (wv & 1) * 32;
    const int wn   = (wv >> 1) * 32;

    const int srow = tid >> 2;
    const int sseg = (tid & 3) * 16;
    int arow = bm + srow; if (arow >= M) arow = M - 1;
    const short* gAh = Ah + (size_t)arow * Ks;
    const short* gWh = Wh + (size_t)(bn + srow) * Ks;
    const int lds_off = srow * LDS_STRIDE + sseg;

    f32x4 acc00 = {0,0,0,0}, acc01 = {0,0,0,0}, acc10 = {0,0,0,0}, acc11 = {0,0,0,0};

    int4 pah0 = *(const int4*)(gAh + sseg), pah1 = *(const int4*)(gAh + sseg + 8);
    int4 pwh0 = *(const int4*)(gWh + sseg), pwh1 = *(const int4*)(gWh + sseg + 8);

    for (int ks = 0; ks < nsteps; ++ks) {
        *(int4*)&sAh[lds_off] = pah0; *(int4*)&sAh[lds_off + 8] = pah1;
        *(int4*)&sWh[lds_off] = pwh0; *(int4*)&sWh[lds_off + 8] = pwh1;
        __syncthreads();
        if (ks + 1 < nsteps) {
            int o = (ks + 1) * 64 + sseg;
            pah0 = *(const int4*)(gAh + o); pah1 = *(const int4*)(gAh + o + 8);
            pwh0 = *(const int4*)(gWh + o); pwh1 = *(const int4*)(gWh + o + 8);
        }
        #pragma unroll
        for (int o = 0; o < 2; ++o) {
            const int a0 = (wm + l16) * LDS_STRIDE + o * 32 + quad * 8;
            const int a1 = a0 + 16 * LDS_STRIDE;
            const int w0 = (wn + l16) * LDS_STRIDE + o * 32 + quad * 8;
            const int w1 = w0 + 16 * LDS_STRIDE;
            bf16x8 ah0 = *(const bf16x8*)&sAh[a0];
            bf16x8 ah1 = *(const bf16x8*)&sAh[a1];
            bf16x8 wh0 = *(const bf16x8*)&sWh[w0];
            bf16x8 wh1 = *(const bf16x8*)&sWh[w1];
            acc00 = __builtin_amdgcn_mfma_f32_16x16x32_bf16(ah0, wh0, acc00, 0, 0, 0);
            acc01 = __builtin_amdgcn_mfma_f32_16x16x32_bf16(ah0, wh1, acc01, 0, 0, 0);
            acc10 = __builtin_amdgcn_mfma_f32_16x16x32_bf16(ah1, wh0, acc10, 0, 0, 0);
            acc11 = __builtin_amdgcn_mfma_f32_16x16x32_bf16(ah1, wh1, acc11, 0, 0, 0);
        }
        __syncthreads();
    }

    const int colb = bn + wn + l16;
    const int rowb = bm + wm + quad * 4;
    const float b0 = bias[colb];
    const float b1 = bias[colb + 16];
    #pragma unroll
    for (int r = 0; r < 4; ++r) {
        int row = rowb + r;
        if (row < M) {
            float v0 = acc00[r] + b0; v0 = v0 > 0.f ? v0 : 0.f;
            float v1 = acc01[r] + b1; v1 = v1 > 0.f ? v1 : 0.f;
            if (mode == 0) {
                Cbf[(size_t)row * HID + colb]      = f2bf(v0);
                Cbf[(size_t)row * HID + colb + 16] = f2bf(v1);
            } else {
                Cf[(size_t)row * HID + colb]      = v0;
                Cf[(size_t)row * HID + colb + 16] = v1;
            }
        }
        int row2 = row + 16;
        if (row2 < M) {
            float v0 = acc10[r] + b0; v0 = v0 > 0.f ? v0 : 0.f;
            float v1 = acc11[r] + b1; v1 = v1 > 0.f ? v1 : 0.f;
            if (mode == 0) {
                Cbf[(size_t)row2 * HID + colb]      = f2bf(v0);
                Cbf[(size_t)row2 * HID + colb + 16] = f2bf(v1);
            } else {
                Cf[(size_t)row2 * HID + colb]      = v0;
                Cf[(size_t)row2 * HID + colb + 16] = v1;
            }
        }
    }
}

// ---------------- launch ----------------

extern "C" void kernel_launch(void* const* d_in, const int* in_sizes, int n_in,
                              void* d_out, int out_size, void* d_ws, size_t ws_size,
                              hipStream_t stream) {
    const float* x  = (const float*)d_in[0];
    const int*   ei = (const int*)d_in[1];
    const float* ew = (const float*)d_in[2];
    const float* W1 = (const float*)d_in[3];
    const float* b1 = (const float*)d_in[4];
    const float* W2 = (const float*)d_in[5];
    const float* b2 = (const float*)d_in[6];
    float* out = (float*)d_out;

    char* ws = (char*)d_ws;
    float* deg      = (float*)(ws);                 // 20000 f32 (becomes dinv)
    int*   counts   = (int*)(ws + 80000);           // 20000 i32
    int*   cursor   = (int*)(ws + 160000);          // 20000 i32
    int*   offs     = (int*)(ws + 240000);          // 20001 i32
    int*   bsum     = (int*)(ws + 320016);          // 20 i32 (pad to 320144)
    int2*  er       = (int2*)(ws + 320144);         // 320000 int2 -> 2880144
    // region A: ax (20000x192 bf16, 7.68MB) dead after gemm1; reused for ah
    short* ax       = (short*)(ws + 2880144);       // -> 10560144
    short* ah       = (short*)(ws + 2880144);       // 20000x256 -> 13120144
    short* h1h      = (short*)(ws + 23360144);      // 20000x256 bf16 -> 33600144
    short* w1b      = (short*)(ws + 33600144);      // 256x192 -> 33698448
    short* w2b      = (short*)(ws + 33698448);      // 256x256 -> 33829520
    short* xb       = (short*)(ws + 34058896);      // 20000x192 bf16 -> 41738896

    hipMemsetAsync(d_ws, 0, 240000, stream);        // deg, counts, cursor

    const int TB = 256;
    prep_all<<<N_NODES + 512 + (N_EDGES + 255) / 256, 256, 0, stream>>>(
        x, xb, W1, W2, w1b, w2b, ei, ew, deg, counts);
    scan_part<<<20, 1024, 0, stream>>>(counts, offs, bsum, deg, N_NODES);
    scan_add<<<20, 1024, 0, stream>>>(bsum, offs, N_NODES);
    scatter_edges<<<(N_EDGES + TB - 1) / TB, TB, 0, stream>>>(ei, ew, deg, offs, cursor, er);

    const int mtiles = (N_NODES + 63) / 64;          // 313
    const int gemm_grid = ((mtiles + 7) / 8) * 32;   // 1280
    // layer 1: Agg(bf16 xb) -> bf16; GEMM(+b1, ReLU) -> h1 bf16
    agg_x<<<N_NODES / 4, 256, 0, stream>>>(xb, deg, offs, er, ax);
    gemm_bf<<<gemm_grid, 256, 0, stream>>>(ax, w1b, b1, nullptr, h1h,
                                           N_NODES, K1P, 3, 0);
    // layer 2: Agg(bf16 h1) -> bf16; GEMM(+b2, ReLU) -> out fp32
    agg_h<<<N_NODES / 4, 256, 0, stream>>>(h1h, deg, offs, er, ah);
    gemm_bf<<<gemm_grid, 256, 0, stream>>>(ah, w2b, b2, out, nullptr,
                                           N_NODES, HID, 4, 1);
}